// Round 2
// baseline (219.668 us; speedup 1.0000x reference)
//
#include <hip/hip_runtime.h>
#include <stdint.h>

typedef unsigned long long u64;
typedef unsigned int u32;
typedef unsigned short u16;
typedef u32 u32x4 __attribute__((ext_vector_type(4)));
typedef float f32x4 __attribute__((ext_vector_type(4)));
typedef int i32x4 __attribute__((ext_vector_type(4)));

// Fixed problem shape (N=100000, E=1600000, C_IN=C_OUT=128, NHEADS=4)
#define CIN 128
#define NN 100000
#define EE 1600000

__device__ __forceinline__ float bf2f(u16 v) {
    union { u32 u; float f; } cv;
    cv.u = ((u32)v) << 16;
    return cv.f;
}

__device__ __forceinline__ u16 f2bf(float f) {      // RNE f32 -> bf16
    u32 b = __float_as_uint(f);
    return (u16)((b + 0x7FFFu + ((b >> 16) & 1u)) >> 16);
}

// Order-preserving bf16 -> u16 map (sign-flip trick). For bf16 bits v:
// mono16(v)<<16 compares identically to mono32(bf2f(v)) for distinct values,
// and equality iff the bf16 values are bit-equal. So the 64-bit key
// (mono16<<48 | ~e) reproduces the old (mono32(sum)<<32 | ~e) ordering:
// within a src group s_j is constant, so argmax(s_j+s_i) == argmax(s_i)
// (f32 add of two bf16s is exact; ties identical).
__device__ __forceinline__ u16 mono16(u16 b) {
    return (b & 0x8000u) ? (u16)~b : (u16)(b | 0x8000u);
}

// ---------------------------------------------------------------------------
// k_s: (a) grid-stride zero of x_out region (nontemporal), seg table, nm;
// (b) V table (W ⊗ att_i only — s_j is dead, see mono16 note) in LDS;
// (c) mono16(s_i) table as ushort4 per node. FMA order per node identical
// to previous version's acc[4..7] -> bit-identical s_i values.
__global__ __launch_bounds__(256, 4) void k_s(const u16* __restrict__ x,
                                              const u16* __restrict__ W,
                                              const u16* __restrict__ att,
                                              ushort4* __restrict__ sib,
                                              u32x4* __restrict__ xout16, int n_xout16,
                                              u32x4* __restrict__ seg16, int n_seg16,
                                              int* __restrict__ nm, int n_nodes) {
    int stride = gridDim.x * blockDim.x;
    int tid = blockIdx.x * blockDim.x + threadIdx.x;
    u32x4 z = { 0, 0, 0, 0 };
    for (int i = tid; i < n_xout16; i += stride) __builtin_nontemporal_store(z, &xout16[i]);
    for (int i = tid; i < n_seg16; i += stride) __builtin_nontemporal_store(z, &seg16[i]);
    for (int i = tid; i < n_nodes; i += stride) nm[i] = 0;

    // ---- V table in LDS (f32), w_i half only ----
    __shared__ float Vl[512];
    for (int slot = threadIdx.x; slot < 512; slot += 256) {
        int k = slot >> 2, head = slot & 3;
        float acc = 0.0f;
        #pragma unroll
        for (int c = 0; c < 32; ++c)
            acc += bf2f(W[k * CIN + head * 32 + c]) * bf2f(att[head * 64 + 32 + c]);
        Vl[slot] = acc;
    }
    __syncthreads();

    for (int n = tid; n < n_nodes; n += stride) {
        const uint4* row = (const uint4*)(x + (size_t)n * CIN);
        float acc[4];
        #pragma unroll
        for (int h = 0; h < 4; ++h) acc[h] = 0.0f;
        #pragma unroll 4
        for (int q = 0; q < 16; ++q) {
            uint4 v = row[q];
            u32 w[4] = { v.x, v.y, v.z, v.w };
            #pragma unroll
            for (int j = 0; j < 4; ++j) {
                float x0 = bf2f((u16)(w[j] & 0xFFFFu));
                float x1 = bf2f((u16)(w[j] >> 16));
                int k0 = q * 8 + j * 2;
                #pragma unroll
                for (int h = 0; h < 4; ++h) acc[h] += x0 * Vl[k0 * 4 + h];
                #pragma unroll
                for (int h = 0; h < 4; ++h) acc[h] += x1 * Vl[(k0 + 1) * 4 + h];
            }
        }
        ushort4 a;
        a.x = mono16(f2bf(acc[0])); a.y = mono16(f2bf(acc[1]));
        a.z = mono16(f2bf(acc[2])); a.w = mono16(f2bf(acc[3]));
        sib[n] = a;
    }
}

// ---------------------------------------------------------------------------
// Single-pass fused argmax, 4 edges/thread for MLP. key=(mono16(s_i)<<48)|~e:
// max score, tie -> min edge id (identical ordering to previous sum-key, since
// s_j[src] is constant within a group). Test-then-atomic with full degree
// visible -> ~H(16)=3.4 atomics/slot. Stale test reads only ever smaller ->
// extra atomic at worst (correct). All 4 edges' ei/gather/seg loads are
// independent -> ~10 outstanding loads per lane instead of a 3-hop serial
// chain per thread. ei streamed nontemporally to keep seg/sib lines in L2.
__global__ __launch_bounds__(256) void k_edge(const int* __restrict__ ei,
                                              const ushort4* __restrict__ sib,
                                              u64* __restrict__ seg, int n_edges) {
    int t = blockIdx.x * blockDim.x + threadIdx.x;
    int e0 = t * 4;
    if (e0 >= n_edges) return;
    i32x4 s4 = __builtin_nontemporal_load(((const i32x4*)ei) + t);
    i32x4 d4 = __builtin_nontemporal_load(((const i32x4*)(ei + n_edges)) + t);

    ushort4 m0 = sib[d4.x];
    ushort4 m1 = sib[d4.y];
    ushort4 m2 = sib[d4.z];
    ushort4 m3 = sib[d4.w];

    u64* r0 = seg + (size_t)s4.x * 4;
    u64* r1 = seg + (size_t)s4.y * 4;
    u64* r2 = seg + (size_t)s4.z * 4;
    u64* r3 = seg + (size_t)s4.w * 4;
    ulonglong2 a0 = *(const ulonglong2*)(r0), b0 = *(const ulonglong2*)(r0 + 2);
    ulonglong2 a1 = *(const ulonglong2*)(r1), b1 = *(const ulonglong2*)(r1 + 2);
    ulonglong2 a2 = *(const ulonglong2*)(r2), b2 = *(const ulonglong2*)(r2 + 2);
    ulonglong2 a3 = *(const ulonglong2*)(r3), b3 = *(const ulonglong2*)(r3 + 2);

    #define EDGE(i, mi, ai, bi, ri) {                                          \
        u64 lo = (u64)(u32)~(u32)(e0 + i);                                     \
        u64 k0 = ((u64)mi.x << 48) | lo;                                       \
        u64 k1 = ((u64)mi.y << 48) | lo;                                       \
        u64 k2 = ((u64)mi.z << 48) | lo;                                       \
        u64 k3 = ((u64)mi.w << 48) | lo;                                       \
        if (k0 > ai.x) atomicMax(&ri[0], k0);                                  \
        if (k1 > ai.y) atomicMax(&ri[1], k1);                                  \
        if (k2 > bi.x) atomicMax(&ri[2], k2);                                  \
        if (k3 > bi.y) atomicMax(&ri[3], k3);                                  \
    }
    EDGE(0, m0, a0, b0, r0)
    EDGE(1, m1, a1, b1, r1)
    EDGE(2, m2, a2, b2, r2)
    EDGE(3, m3, a3, b3, r3)
    #undef EDGE
}

// ---------------------------------------------------------------------------
// Decode winning edge per (src,head); set node_mask[dst].
__global__ void k_select(const int* __restrict__ ei, const u64* __restrict__ seg,
                         int* __restrict__ nm, int n4, int n_edges) {
    int t = blockIdx.x * blockDim.x + threadIdx.x;
    if (t >= n4) return;
    u64 m = seg[t];
    if (m) {
        int e = (int)(~(u32)m);
        nm[ei[n_edges + e]] = 1;     // race-benign: all writers store 1
    }
}

// ---------------------------------------------------------------------------
// Fused epilogue: edge_keep (4 edges/thread, nontemporal f32x4) + node_mask
// f32 + batch_slices f32. ei streamed nontemporally (one-shot, keep nm in L2).
__global__ void k_final(const int* __restrict__ ei, const int* __restrict__ nm,
                        const int* __restrict__ slices, float* __restrict__ out,
                        int n_edges, int n_nodes, int ek_off, int nm_off, int sl_off) {
    int t = blockIdx.x * blockDim.x + threadIdx.x;
    int e0 = 4 * t;
    if (e0 < n_edges) {
        i32x4 srcs = __builtin_nontemporal_load(((const i32x4*)ei) + t);
        i32x4 dsts = __builtin_nontemporal_load(((const i32x4*)(ei + n_edges)) + t);
        f32x4 v;
        v.x = (nm[srcs.x] & nm[dsts.x]) ? 1.0f : 0.0f;
        v.y = (nm[srcs.y] & nm[dsts.y]) ? 1.0f : 0.0f;
        v.z = (nm[srcs.z] & nm[dsts.z]) ? 1.0f : 0.0f;
        v.w = (nm[srcs.w] & nm[dsts.w]) ? 1.0f : 0.0f;
        __builtin_nontemporal_store(v, &((f32x4*)(out + ek_off))[t]);
    }
    if (t < n_nodes) out[nm_off + t] = nm[t] ? 1.0f : 0.0f;
    if (t < 2) out[sl_off + t] = (float)slices[t];   // 0 and 100000, exact
}

// ---------------------------------------------------------------------------
extern "C" void kernel_launch(void* const* d_in, const int* in_sizes, int n_in,
                              void* d_out, int out_size, void* d_ws, size_t ws_size,
                              hipStream_t stream) {
    // Bind inputs by UNIQUE flat size (permutation-proof):
    const u16* x = nullptr; const int* ei = nullptr; const int* sl = nullptr;
    const u16* W = nullptr; const u16* att = nullptr;
    for (int i = 0; i < n_in; ++i) {
        switch (in_sizes[i]) {
            case NN * CIN:   x   = (const u16*)d_in[i]; break;
            case 2 * EE:     ei  = (const int*)d_in[i]; break;
            case 2:          sl  = (const int*)d_in[i]; break;
            case CIN * CIN:  W   = (const u16*)d_in[i]; break;
            case 256:        att = (const u16*)d_in[i]; break;
            default: break;
        }
    }
    if (!x || !ei || !sl || !W || !att) return;

    float* out = (float*)d_out;             // f32 concat, return order
    const int N = NN;
    const int E = EE;
    const int N4 = N * 4;

    // output layout (f32): [x_out N*128][edge_keep E][node_mask N][slices 2]
    const int ek_off = N * CIN;
    const int nm_off = ek_off + E;
    const int sl_off = nm_off + N;

    // workspace (16B-aligned): sib N*8 | nm N*4 | seg N4*8 (seg 64B-aligned:
    // 1200000 % 64 == 0)
    char* ws = (char*)d_ws;
    ushort4* sib = (ushort4*)(ws);
    int*     nm  = (int*)    (ws + (size_t)N * 8);
    u64*     seg = (u64*)    (ws + (size_t)N * 12);

    const int n_xout16 = N * CIN / 4;        // u32x4 count, f32 x_out region
    const int n_seg16  = N4 / 2;             // u32x4 count, seg table

    k_s<<<1280, 256, 0, stream>>>(x, W, att, sib,
                                  (u32x4*)out, n_xout16,
                                  (u32x4*)seg, n_seg16, nm, N);
    k_edge<<<(E / 4 + 255) / 256, 256, 0, stream>>>(ei, sib, seg, E);
    k_select<<<(N4 + 255) / 256, 256, 0, stream>>>(ei, seg, nm, N4, E);
    k_final<<<(E / 4 + 255) / 256, 256, 0, stream>>>(ei, nm, sl, out, E, N, ek_off, nm_off, sl_off);
}